// Round 15
// baseline (302.383 us; speedup 1.0000x reference)
//
#include <hip/hip_runtime.h>
#include <hip/hip_bf16.h>
#include <math.h>

typedef unsigned short ushort_t;
typedef __bf16 bf16x8 __attribute__((ext_vector_type(8)));
typedef float  f32x4  __attribute__((ext_vector_type(4)));
typedef __attribute__((address_space(1))) const unsigned int* gas_t;
typedef __attribute__((address_space(3))) unsigned int* las_t;

#define B_SZ   1024
#define SEQ    17
#define KVN    16
#define HDIM   256
#define NHEAD  8
#define DH     32
#define INF    150
#define OUTD   22
#define LN_EPS 1e-5f
#define N1     (B_SZ * SEQ)      // 17408
#define NN_    100000
#define NKVBLK 1563              // ceil(100000/64)
#define NQBLK  272               // 17408/64

// ---------------- workspace layout (bytes) ----------------
constexpr size_t SZ_H0    = (size_t)NN_ * 256 * 2;
constexpr size_t SZ_KV0   = (size_t)NN_ * 512 * 2;
constexpr size_t SZ_ROW   = (size_t)N1 * 256 * 2;
constexpr size_t OFF_H0   = 0;
constexpr size_t OFF_KV0  = OFF_H0 + SZ_H0;
constexpr size_t OFF_QKV1 = OFF_KV0;                       // alias (KV0 dead after A0)
constexpr size_t OFF_O1   = OFF_QKV1 + (size_t)N1 * 768 * 2;
constexpr size_t OFF_H2   = OFF_O1 + (size_t)B_SZ * 256 * 2;
constexpr size_t OFF_Q0   = OFF_KV0 + SZ_KV0;
constexpr size_t OFF_O0   = OFF_Q0 + SZ_ROW;
constexpr size_t OFF_H1   = OFF_O0;                        // alias (o0 dead after FFN0 stage)
constexpr size_t OFF_IDS  = OFF_O0 + SZ_ROW;
constexpr size_t OFF_WTIN = OFF_IDS + (size_t)N1 * 4;
constexpr size_t OFF_WKV0 = OFF_WTIN + 256 * 160 * 2;
constexpr size_t OFF_WQ0  = OFF_WKV0 + 512 * 256 * 2;
constexpr size_t OFF_WKVQ1= OFF_WQ0 + 256 * 256 * 2;
constexpr size_t OFF_WO0  = OFF_WKVQ1 + 768 * 256 * 2;
constexpr size_t OFF_WF0  = OFF_WO0 + 256 * 256 * 2;
constexpr size_t OFF_WO1  = OFF_WF0 + 256 * 256 * 2;
constexpr size_t OFF_WF1  = OFF_WO1 + 256 * 256 * 2;
constexpr size_t OFF_B1   = OFF_WF1 + 256 * 256 * 2;

__device__ __forceinline__ ushort_t f2bfu(float x) {
    __hip_bfloat16 h = __float2bfloat16(x);
    return *reinterpret_cast<ushort_t*>(&h);
}
__device__ __forceinline__ float bfu2f(ushort_t u) {
    __hip_bfloat16 h;
    *reinterpret_cast<ushort_t*>(&h) = u;
    return __bfloat162float(h);
}
__device__ __forceinline__ f32x4 mfma16(bf16x8 a, bf16x8 b, f32x4 c) {
    return __builtin_amdgcn_mfma_f32_16x16x32_bf16(a, b, c, 0, 0, 0);
}

// ---------------- prep (unchanged) ----------------
__global__ __launch_bounds__(256) void k_prep(
    const float* __restrict__ W_in, const float* __restrict__ Wqkv,
    const float* __restrict__ Wo, const float* __restrict__ Wf,
    const float* __restrict__ bqkv,
    const int* __restrict__ batch, const int* __restrict__ nbr2,
    char* __restrict__ ws) {
    const int job = blockIdx.y;
    const int idx = blockIdx.x * 256 + threadIdx.x;
    if (job == 11) {
        if (idx < N1) {
            int b = idx / SEQ, s = idx % SEQ;
            ((int*)(ws + OFF_IDS))[idx] = (s == 0) ? batch[b] : nbr2[b * KVN + s - 1];
        }
        return;
    }
    if (job == 12) {
        if (idx < 768) ((float*)(ws + OFF_B1))[idx] = bqkv[768 + ((idx + 256) % 768)];
        return;
    }
    const float* src = nullptr; ushort_t* dst = nullptr;
    int Kpad = 256, Kvalid = 256;
    switch (job) {
        case 0:  src = W_in;           dst = (ushort_t*)(ws + OFF_WTIN); Kpad = 160; Kvalid = 150; break;
        case 1:  src = Wqkv + 65536;   dst = (ushort_t*)(ws + OFF_WKV0); break;
        case 2:  src = Wqkv + 131072;  dst = (ushort_t*)(ws + OFF_WKV0) + 65536; break;
        case 3:  src = Wqkv;           dst = (ushort_t*)(ws + OFF_WQ0); break;
        case 4:  src = Wqkv + 262144;  dst = (ushort_t*)(ws + OFF_WKVQ1); break;
        case 5:  src = Wqkv + 327680;  dst = (ushort_t*)(ws + OFF_WKVQ1) + 65536; break;
        case 6:  src = Wqkv + 196608;  dst = (ushort_t*)(ws + OFF_WKVQ1) + 131072; break;
        case 7:  src = Wo;             dst = (ushort_t*)(ws + OFF_WO0); break;
        case 8:  src = Wo + 65536;     dst = (ushort_t*)(ws + OFF_WO1); break;
        case 9:  src = Wf;             dst = (ushort_t*)(ws + OFF_WF0); break;
        case 10: src = Wf + 65536;     dst = (ushort_t*)(ws + OFF_WF1); break;
    }
    const int total = 256 * Kpad;
    if (idx >= total) return;
    int n = idx / Kpad, k = idx % Kpad;
    dst[idx] = (k < Kvalid) ? f2bfu(src[(size_t)k * 256 + n]) : (ushort_t)0;
}

// ====== k_h0: h0 = relu(nf @ W_in + b) — one 64-row tile per block ======
// grid 1563, 256 thr, (256,2): VGPR cap 256 (no spill, natural ~110).
// At VGPR ~110 -> 4 blocks/CU (16 waves/CU).
__global__ __launch_bounds__(256, 2) void k_h0(
    const float* __restrict__ nf, const ushort_t* __restrict__ Wt_in,
    const float* __restrict__ b_in, ushort_t* __restrict__ h0) {
    __shared__ ushort_t As[64 * 192];    // 24 KB: 64 rows x 24 chunks (swizzled)
    const int tid = threadIdx.x;
    const int lane = tid & 63, w = tid >> 6;
    const int lr = lane & 15, q4 = lane >> 4;
    const int m0 = blockIdx.x * 64;

    // stage A: 64 rows x 160 cols f32->bf16 (XOR-swizzled)
    #pragma unroll
    for (int i = 0; i < 5; ++i) {
        int flat = tid + i * 256;        // 1280 chunks = 64 rows x 20
        int row = flat / 20, c = flat % 20;
        int gm = m0 + row; if (gm >= NN_) gm = 0;
        const float* ap = nf + (size_t)gm * INF + c * 8;
        ushort_t tmp[8];
        if (c < 18) {
            #pragma unroll
            for (int j = 0; j < 4; ++j) {
                float2 f = *reinterpret_cast<const float2*>(ap + j * 2);
                tmp[j * 2] = f2bfu(f.x); tmp[j * 2 + 1] = f2bfu(f.y);
            }
        } else {
            #pragma unroll
            for (int j = 0; j < 8; ++j) {
                int k = c * 8 + j;
                tmp[j] = (k < INF) ? f2bfu(ap[j]) : (ushort_t)0;
            }
        }
        *reinterpret_cast<int4*>(&As[row * 192 + (c ^ (row & 7)) * 8]) =
            *reinterpret_cast<int4*>(tmp);
    }
    __syncthreads();

    f32x4 acc[4][4] = {};
    #pragma unroll
    for (int s = 0; s < 5; ++s) {
        bf16x8 a[4], b[4];
        #pragma unroll
        for (int mi = 0; mi < 4; ++mi)
            a[mi] = *reinterpret_cast<const bf16x8*>(
                &As[(mi * 16 + lr) * 192 + (((s * 4 + q4) ^ (lr & 7)) * 8)]);
        #pragma unroll
        for (int ni = 0; ni < 4; ++ni)
            b[ni] = *reinterpret_cast<const bf16x8*>(
                Wt_in + (size_t)(w * 64 + ni * 16 + lr) * 160 + s * 32 + q4 * 8);
        #pragma unroll
        for (int mi = 0; mi < 4; ++mi)
            #pragma unroll
            for (int ni = 0; ni < 4; ++ni)
                acc[mi][ni] = mfma16(a[mi], b[ni], acc[mi][ni]);
    }
    #pragma unroll
    for (int ni = 0; ni < 4; ++ni) {
        float bb = b_in[w * 64 + ni * 16 + lr];
        #pragma unroll
        for (int mi = 0; mi < 4; ++mi)
            #pragma unroll
            for (int r = 0; r < 4; ++r) {
                int grow = m0 + mi * 16 + q4 * 4 + r;
                if (grow < NN_)
                    h0[(size_t)grow * 256 + w * 64 + ni * 16 + lr] =
                        f2bfu(fmaxf(acc[mi][ni][r] + bb, 0.f));
            }
    }
}

// ====== k_kvq (unchanged from r13) ==========================================
__global__ __launch_bounds__(512, 2) void k_kvq(
    const ushort_t* __restrict__ h0, const ushort_t* __restrict__ Wkv,
    const ushort_t* __restrict__ Wq, const float* __restrict__ bqkv,
    const int* __restrict__ ids1, ushort_t* __restrict__ kv0,
    ushort_t* __restrict__ q0) {
    __shared__ ushort_t As[64 * 256];    // 32 KB
    const int tid = threadIdx.x;
    const int lane = tid & 63, w = tid >> 6;
    const int lr = lane & 15, q4 = lane >> 4;
    const bool isv = w >= 4;
    const int n0 = (w & 3) * 64;

    const ushort_t* Wsrc = Wkv + (isv ? 65536 : 0);
    bf16x8 bw[4][8];
    #pragma unroll
    for (int ni = 0; ni < 4; ++ni)
        #pragma unroll
        for (int s = 0; s < 8; ++s)
            bw[ni][s] = *reinterpret_cast<const bf16x8*>(
                Wsrc + (size_t)(n0 + ni * 16 + lr) * 256 + s * 32 + q4 * 8);
    float bb[4];
    #pragma unroll
    for (int ni = 0; ni < 4; ++ni)
        bb[ni] = bqkv[256 + (isv ? 256 : 0) + n0 + ni * 16 + lr];
    const int cbase = (isv ? 256 : 0) + n0;

    for (int t = blockIdx.x; t < NKVBLK; t += 256) {
        const int m0 = t * 64;
        __syncthreads();
        #pragma unroll
        for (int i = 0; i < 4; ++i) {
            int flat = tid + i * 512;
            int row = flat >> 5, ch = flat & 31;
            int gm = m0 + row; if (gm >= NN_) gm = 0;
            const ushort_t* src = h0 + (size_t)gm * 256 + ((ch ^ (row & 7)) * 8);
            __builtin_amdgcn_global_load_lds(
                (gas_t)(const void*)src,
                (las_t)(void*)(As + (size_t)(i * 512 + w * 64) * 8), 16, 0, 0);
        }
        __syncthreads();
        f32x4 acc[4][4] = {};
        #pragma unroll
        for (int s = 0; s < 8; ++s) {
            bf16x8 a[4];
            #pragma unroll
            for (int mi = 0; mi < 4; ++mi)
                a[mi] = *reinterpret_cast<const bf16x8*>(
                    &As[(mi * 16 + lr) * 256 + (((s * 4 + q4) ^ (lr & 7)) * 8)]);
            #pragma unroll
            for (int mi = 0; mi < 4; ++mi)
                #pragma unroll
                for (int ni = 0; ni < 4; ++ni)
                    acc[mi][ni] = mfma16(a[mi], bw[ni][s], acc[mi][ni]);
        }
        #pragma unroll
        for (int ni = 0; ni < 4; ++ni)
            #pragma unroll
            for (int mi = 0; mi < 4; ++mi)
                #pragma unroll
                for (int r = 0; r < 4; ++r) {
                    int grow = m0 + mi * 16 + q4 * 4 + r;
                    if (grow < NN_)
                        kv0[(size_t)grow * 512 + cbase + ni * 16 + lr] =
                            f2bfu(acc[mi][ni][r] + bb[ni]);
                }
    }

    const int n0q = w * 32;
    bf16x8 bq[2][8];
    #pragma unroll
    for (int ni = 0; ni < 2; ++ni)
        #pragma unroll
        for (int s = 0; s < 8; ++s)
            bq[ni][s] = *reinterpret_cast<const bf16x8*>(
                Wq + (size_t)(n0q + ni * 16 + lr) * 256 + s * 32 + q4 * 8);
    float bbq[2];
    #pragma unroll
    for (int ni = 0; ni < 2; ++ni) bbq[ni] = bqkv[n0q + ni * 16 + lr];

    for (int t = blockIdx.x; t < NQBLK; t += 256) {
        const int m0 = t * 64;
        __syncthreads();
        #pragma unroll
        for (int i = 0; i < 4; ++i) {
            int flat = tid + i * 512;
            int row = flat >> 5, ch = flat & 31;
            int rid = ids1[m0 + row];
            const ushort_t* src = h0 + (size_t)rid * 256 + ((ch ^ (row & 7)) * 8);
            __builtin_amdgcn_global_load_lds(
                (gas_t)(const void*)src,
                (las_t)(void*)(As + (size_t)(i * 512 + w * 64) * 8), 16, 0, 0);
        }
        __syncthreads();
        f32x4 acc[4][2] = {};
        #pragma unroll
        for (int s = 0; s < 8; ++s) {
            bf16x8 a[4];
            #pragma unroll
            for (int mi = 0; mi < 4; ++mi)
                a[mi] = *reinterpret_cast<const bf16x8*>(
                    &As[(mi * 16 + lr) * 256 + (((s * 4 + q4) ^ (lr & 7)) * 8)]);
            #pragma unroll
            for (int mi = 0; mi < 4; ++mi)
                #pragma unroll
                for (int ni = 0; ni < 2; ++ni)
                    acc[mi][ni] = mfma16(a[mi], bq[ni][s], acc[mi][ni]);
        }
        #pragma unroll
        for (int ni = 0; ni < 2; ++ni)
            #pragma unroll
            for (int mi = 0; mi < 4; ++mi)
                #pragma unroll
                for (int r = 0; r < 4; ++r) {
                    int grow = m0 + mi * 16 + q4 * 4 + r;
                    q0[(size_t)grow * 256 + n0q + ni * 16 + lr] =
                        f2bfu(acc[mi][ni][r] + bbq[ni]);
                }
    }
}

// ======= k_ffn (unchanged from r13) =======
__global__ __launch_bounds__(256) void k_ffn(
    const ushort_t* __restrict__ Ain, const ushort_t* __restrict__ W1t,
    const float* __restrict__ b1,
    const ushort_t* __restrict__ resmat, const int* __restrict__ residx, int rstride,
    const float* __restrict__ lng1, const float* __restrict__ lnb1,
    const ushort_t* __restrict__ W2t, const float* __restrict__ b2,
    const float* __restrict__ lng2, const float* __restrict__ lnb2,
    ushort_t* __restrict__ out,
    const ushort_t* __restrict__ Wqkv1t, const float* __restrict__ bqkv1,
    ushort_t* __restrict__ qkvout) {
    __shared__ ushort_t Al[32][264];
    __shared__ float xr[32][260];
    __shared__ float mrow[32], rrow[32];
    __shared__ int sidx[32];
    const int tid = threadIdx.x;
    const int m0 = blockIdx.x * 32;
    const int lane = tid & 63, w = tid >> 6;
    const int lr = lane & 15, q4 = lane >> 4, lk = q4 * 8;

    #pragma unroll
    for (int j = 0; j < 4; ++j) {
        int flat = tid + j * 256;
        int row = flat >> 5, ch = flat & 31;
        *reinterpret_cast<int4*>(&Al[row][ch * 8]) =
            *reinterpret_cast<const int4*>(Ain + (size_t)(m0 + row) * 256 + ch * 8);
    }
    if (tid < 32) sidx[tid] = residx ? residx[m0 + tid] : (m0 + tid) * rstride;
    __syncthreads();

    f32x4 acc[2][4];
    #pragma unroll
    for (int g = 0; g < 2; ++g) {
        const ushort_t* Wt = g ? W2t : W1t;
        #pragma unroll
        for (int mi = 0; mi < 2; ++mi)
            #pragma unroll
            for (int ni = 0; ni < 4; ++ni) acc[mi][ni] = f32x4{0.f, 0.f, 0.f, 0.f};
        bf16x8 bc[4];
        #pragma unroll
        for (int ni = 0; ni < 4; ++ni)
            bc[ni] = *reinterpret_cast<const bf16x8*>(
                Wt + (size_t)(w * 64 + ni * 16 + lr) * 256 + lk);
        #pragma unroll
        for (int s = 0; s < 8; ++s) {
            bf16x8 bn[4];
            if (s < 7) {
                #pragma unroll
                for (int ni = 0; ni < 4; ++ni)
                    bn[ni] = *reinterpret_cast<const bf16x8*>(
                        Wt + (size_t)(w * 64 + ni * 16 + lr) * 256 + (s + 1) * 32 + lk);
            }
            bf16x8 a0 = *reinterpret_cast<const bf16x8*>(&Al[lr][s * 32 + lk]);
            bf16x8 a1 = *reinterpret_cast<const bf16x8*>(&Al[16 + lr][s * 32 + lk]);
            #pragma unroll
            for (int ni = 0; ni < 4; ++ni) {
                acc[0][ni] = mfma16(a0, bc[ni], acc[0][ni]);
                acc[1][ni] = mfma16(a1, bc[ni], acc[1][ni]);
            }
            if (s < 7) {
                #pragma unroll
                for (int ni = 0; ni < 4; ++ni) bc[ni] = bn[ni];
            }
        }
        #pragma unroll
        for (int mi = 0; mi < 2; ++mi)
            #pragma unroll
            for (int ni = 0; ni < 4; ++ni)
                #pragma unroll
                for (int r = 0; r < 4; ++r)
                    xr[mi * 16 + q4 * 4 + r][w * 64 + ni * 16 + lr] = acc[mi][ni][r];
        __syncthreads();
        {
            float bb = g ? b2[tid] : b1[tid];
            if (g == 0) {
                for (int r = 0; r < 32; ++r)
                    xr[r][tid] += bb + bfu2f(resmat[(size_t)sidx[r] * 256 + tid]);
            } else {
                for (int r = 0; r < 32; ++r)
                    xr[r][tid] += bb + bfu2f(Al[r][tid]);   // ha residual from LDS
            }
        }
        __syncthreads();
        for (int rr = w * 8; rr < w * 8 + 8; ++rr) {
            float4 v = *reinterpret_cast<const float4*>(&xr[rr][lane * 4]);
            float s1 = v.x + v.y + v.z + v.w;
            float s2 = v.x * v.x + v.y * v.y + v.z * v.z + v.w * v.w;
            #pragma unroll
            for (int off = 32; off > 0; off >>= 1) {
                s1 += __shfl_xor(s1, off);
                s2 += __shfl_xor(s2, off);
            }
            if (lane == 0) {
                float m = s1 * (1.f / 256.f);
                float var = s2 * (1.f / 256.f) - m * m;
                mrow[rr] = m;
                rrow[rr] = rsqrtf(var + LN_EPS);
            }
        }
        __syncthreads();
        if (g == 0) {
            float gg = lng1[tid], bb = lnb1[tid];
            for (int r = 0; r < 32; ++r)
                Al[r][tid] = f2bfu((xr[r][tid] - mrow[r]) * rrow[r] * gg + bb);
        } else {
            float gg = lng2[tid], bb = lnb2[tid];
            for (int r = 0; r < 32; ++r) {
                float v = (xr[r][tid] - mrow[r]) * rrow[r] * gg + bb;
                ushort_t uv = f2bfu(v);
                out[(size_t)(m0 + r) * 256 + tid] = uv;
                if (qkvout) Al[r][tid] = uv;       // h1 tile stays in LDS
            }
        }
        __syncthreads();
    }

    if (qkvout) {
        for (int p = 0; p < 3; ++p) {
            #pragma unroll
            for (int mi = 0; mi < 2; ++mi)
                #pragma unroll
                for (int ni = 0; ni < 4; ++ni) acc[mi][ni] = f32x4{0.f, 0.f, 0.f, 0.f};
            const ushort_t* Wt = Wqkv1t + (size_t)p * 256 * 256;
            bf16x8 bc[4];
            #pragma unroll
            for (int ni = 0; ni < 4; ++ni)
                bc[ni] = *reinterpret_cast<const bf16x8*>(
                    Wt + (size_t)(w * 64 + ni * 16 + lr) * 256 + lk);
            #pragma unroll
            for (int s = 0; s < 8; ++s) {
                bf16x8 bn[4];
                if (s < 7) {
                    #pragma unroll
                    for (int ni = 0; ni < 4; ++ni)
                        bn[ni] = *reinterpret_cast<const bf16x8*>(
                            Wt + (size_t)(w * 64 + ni * 16 + lr) * 256 + (s + 1) * 32 + lk);
                }
                bf16x8 a0 = *reinterpret_cast<const bf16x8*>(&Al[lr][s * 32 + lk]);
                bf16x8 a1 = *reinterpret_cast<const bf16x8*>(&Al[16 + lr][s * 32 + lk]);
                #pragma unroll
                for (int ni = 0; ni < 4; ++ni) {
                    acc[0][ni] = mfma16(a0, bc[ni], acc[0][ni]);
                    acc[1][ni] = mfma16(a1, bc[ni], acc[1][ni]);
                }
                if (s < 7) {
                    #pragma unroll
                    for (int ni = 0; ni < 4; ++ni) bc[ni] = bn[ni];
                }
            }
            #pragma unroll
            for (int ni = 0; ni < 4; ++ni) {
                int col = w * 64 + ni * 16 + lr;
                float bb = bqkv1[p * 256 + col];
                #pragma unroll
                for (int mi = 0; mi < 2; ++mi)
                    #pragma unroll
                    for (int r = 0; r < 4; ++r) {
                        int row = m0 + mi * 16 + q4 * 4 + r;
                        qkvout[(size_t)row * 768 + p * 256 + col] =
                            f2bfu(acc[mi][ni][r] + bb);
                    }
            }
        }
    }
}

// ---------------- attention: one wave per group (unchanged) ----------------
__global__ __launch_bounds__(256) void attn_wave(
    const ushort_t* __restrict__ q_all, int qld, int qoff, int qstride,
    const ushort_t* __restrict__ kv_all, int kvld, int koff, int voff,
    const int* __restrict__ kvidx, int ngroups, ushort_t* __restrict__ o_out) {
    __shared__ ushort_t KL[4][KVN][264];
    __shared__ ushort_t VL[4][KVN][264];
    const int w = threadIdx.x >> 6, lane = threadIdx.x & 63;
    const int g = blockIdx.x * 4 + w;
    if (g >= ngroups) return;

    int idx16 = 0;
    if (lane < KVN)
        idx16 = kvidx ? kvidx[g * KVN + lane] : g * SEQ + 1 + lane;

    float qv[4];
    {
        uint2 u = *reinterpret_cast<const uint2*>(
            q_all + (size_t)g * qstride * qld + qoff + lane * 4);
        qv[0] = bfu2f((ushort_t)(u.x & 0xffff));
        qv[1] = bfu2f((ushort_t)(u.x >> 16));
        qv[2] = bfu2f((ushort_t)(u.y & 0xffff));
        qv[3] = bfu2f((ushort_t)(u.y >> 16));
    }
    {
        const int r = lane & 15, qtr = lane >> 4;
        int rid = __shfl(idx16, r);
        const ushort_t* kb = kv_all + (size_t)rid * kvld + koff;
        const ushort_t* vb = kv_all + (size_t)rid * kvld + voff;
        #pragma unroll
        for (int j = 0; j < 8; ++j) {
            int c8 = (qtr * 8 + j) * 8;
            *reinterpret_cast<int4*>(&KL[w][r][c8]) = *reinterpret_cast<const int4*>(kb + c8);
            *reinterpret_cast<int4*>(&VL[w][r][c8]) = *reinterpret_cast<const int4*>(vb + c8);
        }
    }
    float att[KVN];
    #pragma unroll
    for (int k = 0; k < KVN; ++k) {
        uint2 u = *reinterpret_cast<const uint2*>(&KL[w][k][lane * 4]);
        float p = qv[0] * bfu2f((ushort_t)(u.x & 0xffff))
                + qv[1] * bfu2f((ushort_t)(u.x >> 16))
                + qv[2] * bfu2f((ushort_t)(u.y & 0xffff))
                + qv[3] * bfu2f((ushort_t)(u.y >> 16));
        p += __shfl_xor(p, 1);
        p += __shfl_xor(p, 2);
        p += __shfl_xor(p, 4);
        att[k] = p * 0.17677669529663687f;
    }
    float m = att[0];
    #pragma unroll
    for (int k = 1; k < KVN; ++k) m = fmaxf(m, att[k]);
    float sum = 0.f;
    #pragma unroll
    for (int k = 0; k < KVN; ++k) { att[k] = __expf(att[k] - m); sum += att[k]; }
    float inv = 1.f / sum;
    float o[4] = {0.f, 0.f, 0.f, 0.f};
    #pragma unroll
    for (int k = 0; k < KVN; ++k) {
        uint2 u = *reinterpret_cast<const uint2*>(&VL[w][k][lane * 4]);
        float a = att[k] * inv;
        o[0] += a * bfu2f((ushort_t)(u.x & 0xffff));
        o[1] += a * bfu2f((ushort_t)(u.x >> 16));
        o[2] += a * bfu2f((ushort_t)(u.y & 0xffff));
        o[3] += a * bfu2f((ushort_t)(u.y >> 16));
    }
    uint2 r;
    r.x = (unsigned)f2bfu(o[0]) | ((unsigned)f2bfu(o[1]) << 16);
    r.y = (unsigned)f2bfu(o[2]) | ((unsigned)f2bfu(o[3]) << 16);
    *reinterpret_cast<uint2*>(o_out + (size_t)g * 256 + lane * 4) = r;
}

// ---------------- output head (unchanged) ----------------
__global__ __launch_bounds__(64) void k_out(
    const ushort_t* __restrict__ h2, const float* __restrict__ W_out,
    const float* __restrict__ b_out, float* __restrict__ out) {
    const int b = blockIdx.x, j = threadIdx.x;
    __shared__ float xr[HDIM];
    for (int k = j; k < HDIM; k += 64) xr[k] = bfu2f(h2[(size_t)b * HDIM + k]);
    __syncthreads();
    float logit = -1e30f;
    if (j < OUTD) {
        float acc = b_out[j];
        for (int k = 0; k < HDIM; ++k) acc += xr[k] * W_out[k * OUTD + j];
        logit = acc;
    }
    float m = logit;
    #pragma unroll
    for (int off = 32; off > 0; off >>= 1) m = fmaxf(m, __shfl_xor(m, off));
    float e = (j < OUTD) ? __expf(logit - m) : 0.f;
    float s = e;
    #pragma unroll
    for (int off = 32; off > 0; off >>= 1) s += __shfl_xor(s, off);
    if (j < OUTD) out[(size_t)b * OUTD + j] = e / s;
}

extern "C" void kernel_launch(void* const* d_in, const int* in_sizes, int n_in,
                              void* d_out, int out_size, void* d_ws, size_t ws_size,
                              hipStream_t stream) {
    const float* nf    = (const float*)d_in[0];
    const int*   batch = (const int*)d_in[1];
    const int*   nbr2  = (const int*)d_in[2];
    const int*   nbr1  = (const int*)d_in[3];
    const float* W_in  = (const float*)d_in[4];
    const float* b_in  = (const float*)d_in[5];
    const float* Wqkv  = (const float*)d_in[6];
    const float* bqkv  = (const float*)d_in[7];
    const float* Wo    = (const float*)d_in[8];
    const float* bo    = (const float*)d_in[9];
    const float* Wf    = (const float*)d_in[10];
    const float* bf    = (const float*)d_in[11];
    const float* ln_g  = (const float*)d_in[12];
    const float* ln_b  = (const float*)d_in[13];
    const float* W_out = (const float*)d_in[14];
    const float* b_out = (const float*)d_in[15];
    float* out = (float*)d_out;
    char* ws = (char*)d_ws;

    ushort_t* h0   = (ushort_t*)(ws + OFF_H0);
    ushort_t* kv0  = (ushort_t*)(ws + OFF_KV0);
    ushort_t* q0   = (ushort_t*)(ws + OFF_Q0);
    ushort_t* o0   = (ushort_t*)(ws + OFF_O0);
    ushort_t* h1   = (ushort_t*)(ws + OFF_H1);
    ushort_t* qkv1 = (ushort_t*)(ws + OFF_QKV1);
    ushort_t* o1   = (ushort_t*)(ws + OFF_O1);
    ushort_t* h2   = (ushort_t*)(ws + OFF_H2);
    const int* ids1 = (const int*)(ws + OFF_IDS);

    hipLaunchKernelGGL(k_prep, dim3(256, 13), dim3(256), 0, stream,
                       W_in, Wqkv, Wo, Wf, bqkv, batch, nbr2, ws);
    // h0 = relu(nf @ W_in + b): one tile per block, (256,2)
    hipLaunchKernelGGL(k_h0, dim3(NKVBLK), dim3(256), 0, stream,
                       nf, (const ushort_t*)(ws + OFF_WTIN), b_in, h0);
    // kv0 + q0 (weight-stationary)
    hipLaunchKernelGGL(k_kvq, dim3(256), dim3(512), 0, stream,
                       h0, (const ushort_t*)(ws + OFF_WKV0),
                       (const ushort_t*)(ws + OFF_WQ0), bqkv, ids1, kv0, q0);
    // A0
    hipLaunchKernelGGL(attn_wave, dim3(N1 / 4), dim3(256), 0, stream,
                       q0, 256, 0, 1, kv0, 512, 0, 256, nbr1, N1, o0);
    // FFN0 (+ fused qkv1), residual = h0[ids1]
    hipLaunchKernelGGL(k_ffn, dim3(N1 / 32), dim3(256), 0, stream,
                       o0, (const ushort_t*)(ws + OFF_WO0), bo,
                       h0, ids1, 1, ln_g, ln_b,
                       (const ushort_t*)(ws + OFF_WF0), bf,
                       ln_g + 256, ln_b + 256, h1,
                       (const ushort_t*)(ws + OFF_WKVQ1),
                       (const float*)(ws + OFF_B1), qkv1);
    // A1
    hipLaunchKernelGGL(attn_wave, dim3(B_SZ / 4), dim3(256), 0, stream,
                       qkv1, 768, 512, 17, qkv1, 768, 0, 256,
                       (const int*)nullptr, B_SZ, o1);
    // FFN1 (no qkv), residual = h1[17b]
    hipLaunchKernelGGL(k_ffn, dim3(B_SZ / 32), dim3(256), 0, stream,
                       o1, (const ushort_t*)(ws + OFF_WO1), bo + 256,
                       h1, (const int*)nullptr, 17, ln_g + 512, ln_b + 512,
                       (const ushort_t*)(ws + OFF_WF1), bf + 256,
                       ln_g + 768, ln_b + 768, h2,
                       (const ushort_t*)nullptr, (const float*)nullptr,
                       (ushort_t*)nullptr);
    hipLaunchKernelGGL(k_out, dim3(B_SZ), dim3(64), 0, stream,
                       h2, W_out, b_out, out);
}

// Round 16
// 284.046 us; speedup vs baseline: 1.0646x; 1.0646x over previous
//
#include <hip/hip_runtime.h>
#include <hip/hip_bf16.h>
#include <math.h>

typedef unsigned short ushort_t;
typedef __bf16 bf16x8 __attribute__((ext_vector_type(8)));
typedef float  f32x4  __attribute__((ext_vector_type(4)));
typedef __attribute__((address_space(1))) const unsigned int* gas_t;
typedef __attribute__((address_space(3))) unsigned int* las_t;

#define B_SZ   1024
#define SEQ    17
#define KVN    16
#define HDIM   256
#define NHEAD  8
#define DH     32
#define INF    150
#define OUTD   22
#define LN_EPS 1e-5f
#define N1     (B_SZ * SEQ)      // 17408
#define NN_    100000
#define NKVBLK 1563              // ceil(100000/64)
#define NQBLK  272               // 17408/64
#define H0GRID 1024              // k_h0 blocks (2 tiles each)

// ---------------- workspace layout (bytes) ----------------
constexpr size_t SZ_H0    = (size_t)NN_ * 256 * 2;
constexpr size_t SZ_KV0   = (size_t)NN_ * 512 * 2;
constexpr size_t SZ_ROW   = (size_t)N1 * 256 * 2;
constexpr size_t OFF_H0   = 0;
constexpr size_t OFF_KV0  = OFF_H0 + SZ_H0;
constexpr size_t OFF_QKV1 = OFF_KV0;                       // alias (KV0 dead after A0)
constexpr size_t OFF_O1   = OFF_QKV1 + (size_t)N1 * 768 * 2;
constexpr size_t OFF_H2   = OFF_O1 + (size_t)B_SZ * 256 * 2;
constexpr size_t OFF_Q0   = OFF_KV0 + SZ_KV0;
constexpr size_t OFF_O0   = OFF_Q0 + SZ_ROW;
constexpr size_t OFF_H1   = OFF_O0;                        // alias (o0 dead after FFN0 stage)
constexpr size_t OFF_IDS  = OFF_O0 + SZ_ROW;
constexpr size_t OFF_WTIN = OFF_IDS + (size_t)N1 * 4;
constexpr size_t OFF_WKV0 = OFF_WTIN + 256 * 160 * 2;
constexpr size_t OFF_WQ0  = OFF_WKV0 + 512 * 256 * 2;
constexpr size_t OFF_WKVQ1= OFF_WQ0 + 256 * 256 * 2;
constexpr size_t OFF_WO0  = OFF_WKVQ1 + 768 * 256 * 2;
constexpr size_t OFF_WF0  = OFF_WO0 + 256 * 256 * 2;
constexpr size_t OFF_WO1  = OFF_WF0 + 256 * 256 * 2;
constexpr size_t OFF_WF1  = OFF_WO1 + 256 * 256 * 2;
constexpr size_t OFF_B1   = OFF_WF1 + 256 * 256 * 2;

__device__ __forceinline__ ushort_t f2bfu(float x) {
    __hip_bfloat16 h = __float2bfloat16(x);
    return *reinterpret_cast<ushort_t*>(&h);
}
__device__ __forceinline__ float bfu2f(ushort_t u) {
    __hip_bfloat16 h;
    *reinterpret_cast<ushort_t*>(&h) = u;
    return __bfloat162float(h);
}
__device__ __forceinline__ f32x4 mfma16(bf16x8 a, bf16x8 b, f32x4 c) {
    return __builtin_amdgcn_mfma_f32_16x16x32_bf16(a, b, c, 0, 0, 0);
}

// ---------------- prep (unchanged) ----------------
__global__ __launch_bounds__(256) void k_prep(
    const float* __restrict__ W_in, const float* __restrict__ Wqkv,
    const float* __restrict__ Wo, const float* __restrict__ Wf,
    const float* __restrict__ bqkv,
    const int* __restrict__ batch, const int* __restrict__ nbr2,
    char* __restrict__ ws) {
    const int job = blockIdx.y;
    const int idx = blockIdx.x * 256 + threadIdx.x;
    if (job == 11) {
        if (idx < N1) {
            int b = idx / SEQ, s = idx % SEQ;
            ((int*)(ws + OFF_IDS))[idx] = (s == 0) ? batch[b] : nbr2[b * KVN + s - 1];
        }
        return;
    }
    if (job == 12) {
        if (idx < 768) ((float*)(ws + OFF_B1))[idx] = bqkv[768 + ((idx + 256) % 768)];
        return;
    }
    const float* src = nullptr; ushort_t* dst = nullptr;
    int Kpad = 256, Kvalid = 256;
    switch (job) {
        case 0:  src = W_in;           dst = (ushort_t*)(ws + OFF_WTIN); Kpad = 160; Kvalid = 150; break;
        case 1:  src = Wqkv + 65536;   dst = (ushort_t*)(ws + OFF_WKV0); break;
        case 2:  src = Wqkv + 131072;  dst = (ushort_t*)(ws + OFF_WKV0) + 65536; break;
        case 3:  src = Wqkv;           dst = (ushort_t*)(ws + OFF_WQ0); break;
        case 4:  src = Wqkv + 262144;  dst = (ushort_t*)(ws + OFF_WKVQ1); break;
        case 5:  src = Wqkv + 327680;  dst = (ushort_t*)(ws + OFF_WKVQ1) + 65536; break;
        case 6:  src = Wqkv + 196608;  dst = (ushort_t*)(ws + OFF_WKVQ1) + 131072; break;
        case 7:  src = Wo;             dst = (ushort_t*)(ws + OFF_WO0); break;
        case 8:  src = Wo + 65536;     dst = (ushort_t*)(ws + OFF_WO1); break;
        case 9:  src = Wf;             dst = (ushort_t*)(ws + OFF_WF0); break;
        case 10: src = Wf + 65536;     dst = (ushort_t*)(ws + OFF_WF1); break;
    }
    const int total = 256 * Kpad;
    if (idx >= total) return;
    int n = idx / Kpad, k = idx % Kpad;
    dst[idx] = (k < Kvalid) ? f2bfu(src[(size_t)k * 256 + n]) : (ushort_t)0;
}

// ====== k_h0: h0 = relu(nf @ W_in + b), weight-stationary persistent ======
// r13 body exactly; grid 512 -> 1024 (2 tiles/block) for 2x blocks/CU.
__global__ __launch_bounds__(256, 2) void k_h0(
    const float* __restrict__ nf, const ushort_t* __restrict__ Wt_in,
    const float* __restrict__ b_in, ushort_t* __restrict__ h0) {
    __shared__ ushort_t As[64 * 192];    // 24 KB: 64 rows x 24 chunks (swizzled)
    const int tid = threadIdx.x;
    const int lane = tid & 63, w = tid >> 6;
    const int lr = lane & 15, q4 = lane >> 4;

    bf16x8 bw[4][5];
    #pragma unroll
    for (int ni = 0; ni < 4; ++ni)
        #pragma unroll
        for (int s = 0; s < 5; ++s)
            bw[ni][s] = *reinterpret_cast<const bf16x8*>(
                Wt_in + (size_t)(w * 64 + ni * 16 + lr) * 160 + s * 32 + q4 * 8);
    float bb[4];
    #pragma unroll
    for (int ni = 0; ni < 4; ++ni) bb[ni] = b_in[w * 64 + ni * 16 + lr];

    for (int t = blockIdx.x; t < NKVBLK; t += H0GRID) {
        const int m0 = t * 64;
        __syncthreads();                     // prior tile's readers done
        #pragma unroll
        for (int i = 0; i < 5; ++i) {
            int flat = tid + i * 256;        // 1280 chunks = 64 rows x 20
            int row = flat / 20, c = flat % 20;
            int gm = m0 + row; if (gm >= NN_) gm = 0;
            const float* ap = nf + (size_t)gm * INF + c * 8;
            ushort_t tmp[8];
            if (c < 18) {
                #pragma unroll
                for (int j = 0; j < 4; ++j) {
                    float2 f = *reinterpret_cast<const float2*>(ap + j * 2);
                    tmp[j * 2] = f2bfu(f.x); tmp[j * 2 + 1] = f2bfu(f.y);
                }
            } else {
                #pragma unroll
                for (int j = 0; j < 8; ++j) {
                    int k = c * 8 + j;
                    tmp[j] = (k < INF) ? f2bfu(ap[j]) : (ushort_t)0;
                }
            }
            *reinterpret_cast<int4*>(&As[row * 192 + (c ^ (row & 7)) * 8]) =
                *reinterpret_cast<int4*>(tmp);
        }
        __syncthreads();
        f32x4 acc[4][4] = {};
        #pragma unroll
        for (int s = 0; s < 5; ++s) {
            bf16x8 a[4];
            #pragma unroll
            for (int mi = 0; mi < 4; ++mi)
                a[mi] = *reinterpret_cast<const bf16x8*>(
                    &As[(mi * 16 + lr) * 192 + (((s * 4 + q4) ^ (lr & 7)) * 8)]);
            #pragma unroll
            for (int mi = 0; mi < 4; ++mi)
                #pragma unroll
                for (int ni = 0; ni < 4; ++ni)
                    acc[mi][ni] = mfma16(a[mi], bw[ni][s], acc[mi][ni]);
        }
        #pragma unroll
        for (int ni = 0; ni < 4; ++ni)
            #pragma unroll
            for (int mi = 0; mi < 4; ++mi)
                #pragma unroll
                for (int r = 0; r < 4; ++r) {
                    int grow = m0 + mi * 16 + q4 * 4 + r;
                    if (grow < NN_)
                        h0[(size_t)grow * 256 + w * 64 + ni * 16 + lr] =
                            f2bfu(fmaxf(acc[mi][ni][r] + bb[ni], 0.f));
                }
    }
}

// ====== k_kvq (unchanged from r13) ==========================================
__global__ __launch_bounds__(512, 2) void k_kvq(
    const ushort_t* __restrict__ h0, const ushort_t* __restrict__ Wkv,
    const ushort_t* __restrict__ Wq, const float* __restrict__ bqkv,
    const int* __restrict__ ids1, ushort_t* __restrict__ kv0,
    ushort_t* __restrict__ q0) {
    __shared__ ushort_t As[64 * 256];    // 32 KB
    const int tid = threadIdx.x;
    const int lane = tid & 63, w = tid >> 6;
    const int lr = lane & 15, q4 = lane >> 4;
    const bool isv = w >= 4;
    const int n0 = (w & 3) * 64;

    const ushort_t* Wsrc = Wkv + (isv ? 65536 : 0);
    bf16x8 bw[4][8];
    #pragma unroll
    for (int ni = 0; ni < 4; ++ni)
        #pragma unroll
        for (int s = 0; s < 8; ++s)
            bw[ni][s] = *reinterpret_cast<const bf16x8*>(
                Wsrc + (size_t)(n0 + ni * 16 + lr) * 256 + s * 32 + q4 * 8);
    float bb[4];
    #pragma unroll
    for (int ni = 0; ni < 4; ++ni)
        bb[ni] = bqkv[256 + (isv ? 256 : 0) + n0 + ni * 16 + lr];
    const int cbase = (isv ? 256 : 0) + n0;

    for (int t = blockIdx.x; t < NKVBLK; t += 256) {
        const int m0 = t * 64;
        __syncthreads();
        #pragma unroll
        for (int i = 0; i < 4; ++i) {
            int flat = tid + i * 512;
            int row = flat >> 5, ch = flat & 31;
            int gm = m0 + row; if (gm >= NN_) gm = 0;
            const ushort_t* src = h0 + (size_t)gm * 256 + ((ch ^ (row & 7)) * 8);
            __builtin_amdgcn_global_load_lds(
                (gas_t)(const void*)src,
                (las_t)(void*)(As + (size_t)(i * 512 + w * 64) * 8), 16, 0, 0);
        }
        __syncthreads();
        f32x4 acc[4][4] = {};
        #pragma unroll
        for (int s = 0; s < 8; ++s) {
            bf16x8 a[4];
            #pragma unroll
            for (int mi = 0; mi < 4; ++mi)
                a[mi] = *reinterpret_cast<const bf16x8*>(
                    &As[(mi * 16 + lr) * 256 + (((s * 4 + q4) ^ (lr & 7)) * 8)]);
            #pragma unroll
            for (int mi = 0; mi < 4; ++mi)
                #pragma unroll
                for (int ni = 0; ni < 4; ++ni)
                    acc[mi][ni] = mfma16(a[mi], bw[ni][s], acc[mi][ni]);
        }
        #pragma unroll
        for (int ni = 0; ni < 4; ++ni)
            #pragma unroll
            for (int mi = 0; mi < 4; ++mi)
                #pragma unroll
                for (int r = 0; r < 4; ++r) {
                    int grow = m0 + mi * 16 + q4 * 4 + r;
                    if (grow < NN_)
                        kv0[(size_t)grow * 512 + cbase + ni * 16 + lr] =
                            f2bfu(acc[mi][ni][r] + bb[ni]);
                }
    }

    const int n0q = w * 32;
    bf16x8 bq[2][8];
    #pragma unroll
    for (int ni = 0; ni < 2; ++ni)
        #pragma unroll
        for (int s = 0; s < 8; ++s)
            bq[ni][s] = *reinterpret_cast<const bf16x8*>(
                Wq + (size_t)(n0q + ni * 16 + lr) * 256 + s * 32 + q4 * 8);
    float bbq[2];
    #pragma unroll
    for (int ni = 0; ni < 2; ++ni) bbq[ni] = bqkv[n0q + ni * 16 + lr];

    for (int t = blockIdx.x; t < NQBLK; t += 256) {
        const int m0 = t * 64;
        __syncthreads();
        #pragma unroll
        for (int i = 0; i < 4; ++i) {
            int flat = tid + i * 512;
            int row = flat >> 5, ch = flat & 31;
            int rid = ids1[m0 + row];
            const ushort_t* src = h0 + (size_t)rid * 256 + ((ch ^ (row & 7)) * 8);
            __builtin_amdgcn_global_load_lds(
                (gas_t)(const void*)src,
                (las_t)(void*)(As + (size_t)(i * 512 + w * 64) * 8), 16, 0, 0);
        }
        __syncthreads();
        f32x4 acc[4][2] = {};
        #pragma unroll
        for (int s = 0; s < 8; ++s) {
            bf16x8 a[4];
            #pragma unroll
            for (int mi = 0; mi < 4; ++mi)
                a[mi] = *reinterpret_cast<const bf16x8*>(
                    &As[(mi * 16 + lr) * 256 + (((s * 4 + q4) ^ (lr & 7)) * 8)]);
            #pragma unroll
            for (int mi = 0; mi < 4; ++mi)
                #pragma unroll
                for (int ni = 0; ni < 2; ++ni)
                    acc[mi][ni] = mfma16(a[mi], bq[ni][s], acc[mi][ni]);
        }
        #pragma unroll
        for (int ni = 0; ni < 2; ++ni)
            #pragma unroll
            for (int mi = 0; mi < 4; ++mi)
                #pragma unroll
                for (int r = 0; r < 4; ++r) {
                    int grow = m0 + mi * 16 + q4 * 4 + r;
                    q0[(size_t)grow * 256 + n0q + ni * 16 + lr] =
                        f2bfu(acc[mi][ni][r] + bbq[ni]);
                }
    }
}

// ======= k_ffn (unchanged from r13) =======
__global__ __launch_bounds__(256) void k_ffn(
    const ushort_t* __restrict__ Ain, const ushort_t* __restrict__ W1t,
    const float* __restrict__ b1,
    const ushort_t* __restrict__ resmat, const int* __restrict__ residx, int rstride,
    const float* __restrict__ lng1, const float* __restrict__ lnb1,
    const ushort_t* __restrict__ W2t, const float* __restrict__ b2,
    const float* __restrict__ lng2, const float* __restrict__ lnb2,
    ushort_t* __restrict__ out,
    const ushort_t* __restrict__ Wqkv1t, const float* __restrict__ bqkv1,
    ushort_t* __restrict__ qkvout) {
    __shared__ ushort_t Al[32][264];
    __shared__ float xr[32][260];
    __shared__ float mrow[32], rrow[32];
    __shared__ int sidx[32];
    const int tid = threadIdx.x;
    const int m0 = blockIdx.x * 32;
    const int lane = tid & 63, w = tid >> 6;
    const int lr = lane & 15, q4 = lane >> 4, lk = q4 * 8;

    #pragma unroll
    for (int j = 0; j < 4; ++j) {
        int flat = tid + j * 256;
        int row = flat >> 5, ch = flat & 31;
        *reinterpret_cast<int4*>(&Al[row][ch * 8]) =
            *reinterpret_cast<const int4*>(Ain + (size_t)(m0 + row) * 256 + ch * 8);
    }
    if (tid < 32) sidx[tid] = residx ? residx[m0 + tid] : (m0 + tid) * rstride;
    __syncthreads();

    f32x4 acc[2][4];
    #pragma unroll
    for (int g = 0; g < 2; ++g) {
        const ushort_t* Wt = g ? W2t : W1t;
        #pragma unroll
        for (int mi = 0; mi < 2; ++mi)
            #pragma unroll
            for (int ni = 0; ni < 4; ++ni) acc[mi][ni] = f32x4{0.f, 0.f, 0.f, 0.f};
        bf16x8 bc[4];
        #pragma unroll
        for (int ni = 0; ni < 4; ++ni)
            bc[ni] = *reinterpret_cast<const bf16x8*>(
                Wt + (size_t)(w * 64 + ni * 16 + lr) * 256 + lk);
        #pragma unroll
        for (int s = 0; s < 8; ++s) {
            bf16x8 bn[4];
            if (s < 7) {
                #pragma unroll
                for (int ni = 0; ni < 4; ++ni)
                    bn[ni] = *reinterpret_cast<const bf16x8*>(
                        Wt + (size_t)(w * 64 + ni * 16 + lr) * 256 + (s + 1) * 32 + lk);
            }
            bf16x8 a0 = *reinterpret_cast<const bf16x8*>(&Al[lr][s * 32 + lk]);
            bf16x8 a1 = *reinterpret_cast<const bf16x8*>(&Al[16 + lr][s * 32 + lk]);
            #pragma unroll
            for (int ni = 0; ni < 4; ++ni) {
                acc[0][ni] = mfma16(a0, bc[ni], acc[0][ni]);
                acc[1][ni] = mfma16(a1, bc[ni], acc[1][ni]);
            }
            if (s < 7) {
                #pragma unroll
                for (int ni = 0; ni < 4; ++ni) bc[ni] = bn[ni];
            }
        }
        #pragma unroll
        for (int mi = 0; mi < 2; ++mi)
            #pragma unroll
            for (int ni = 0; ni < 4; ++ni)
                #pragma unroll
                for (int r = 0; r < 4; ++r)
                    xr[mi * 16 + q4 * 4 + r][w * 64 + ni * 16 + lr] = acc[mi][ni][r];
        __syncthreads();
        {
            float bb = g ? b2[tid] : b1[tid];
            if (g == 0) {
                for (int r = 0; r < 32; ++r)
                    xr[r][tid] += bb + bfu2f(resmat[(size_t)sidx[r] * 256 + tid]);
            } else {
                for (int r = 0; r < 32; ++r)
                    xr[r][tid] += bb + bfu2f(Al[r][tid]);   // ha residual from LDS
            }
        }
        __syncthreads();
        for (int rr = w * 8; rr < w * 8 + 8; ++rr) {
            float4 v = *reinterpret_cast<const float4*>(&xr[rr][lane * 4]);
            float s1 = v.x + v.y + v.z + v.w;
            float s2 = v.x * v.x + v.y * v.y + v.z * v.z + v.w * v.w;
            #pragma unroll
            for (int off = 32; off > 0; off >>= 1) {
                s1 += __shfl_xor(s1, off);
                s2 += __shfl_xor(s2, off);
            }
            if (lane == 0) {
                float m = s1 * (1.f / 256.f);
                float var = s2 * (1.f / 256.f) - m * m;
                mrow[rr] = m;
                rrow[rr] = rsqrtf(var + LN_EPS);
            }
        }
        __syncthreads();
        if (g == 0) {
            float gg = lng1[tid], bb = lnb1[tid];
            for (int r = 0; r < 32; ++r)
                Al[r][tid] = f2bfu((xr[r][tid] - mrow[r]) * rrow[r] * gg + bb);
        } else {
            float gg = lng2[tid], bb = lnb2[tid];
            for (int r = 0; r < 32; ++r) {
                float v = (xr[r][tid] - mrow[r]) * rrow[r] * gg + bb;
                ushort_t uv = f2bfu(v);
                out[(size_t)(m0 + r) * 256 + tid] = uv;
                if (qkvout) Al[r][tid] = uv;       // h1 tile stays in LDS
            }
        }
        __syncthreads();
    }

    if (qkvout) {
        for (int p = 0; p < 3; ++p) {
            #pragma unroll
            for (int mi = 0; mi < 2; ++mi)
                #pragma unroll
                for (int ni = 0; ni < 4; ++ni) acc[mi][ni] = f32x4{0.f, 0.f, 0.f, 0.f};
            const ushort_t* Wt = Wqkv1t + (size_t)p * 256 * 256;
            bf16x8 bc[4];
            #pragma unroll
            for (int ni = 0; ni < 4; ++ni)
                bc[ni] = *reinterpret_cast<const bf16x8*>(
                    Wt + (size_t)(w * 64 + ni * 16 + lr) * 256 + lk);
            #pragma unroll
            for (int s = 0; s < 8; ++s) {
                bf16x8 bn[4];
                if (s < 7) {
                    #pragma unroll
                    for (int ni = 0; ni < 4; ++ni)
                        bn[ni] = *reinterpret_cast<const bf16x8*>(
                            Wt + (size_t)(w * 64 + ni * 16 + lr) * 256 + (s + 1) * 32 + lk);
                }
                bf16x8 a0 = *reinterpret_cast<const bf16x8*>(&Al[lr][s * 32 + lk]);
                bf16x8 a1 = *reinterpret_cast<const bf16x8*>(&Al[16 + lr][s * 32 + lk]);
                #pragma unroll
                for (int ni = 0; ni < 4; ++ni) {
                    acc[0][ni] = mfma16(a0, bc[ni], acc[0][ni]);
                    acc[1][ni] = mfma16(a1, bc[ni], acc[1][ni]);
                }
                if (s < 7) {
                    #pragma unroll
                    for (int ni = 0; ni < 4; ++ni) bc[ni] = bn[ni];
                }
            }
            #pragma unroll
            for (int ni = 0; ni < 4; ++ni) {
                int col = w * 64 + ni * 16 + lr;
                float bb = bqkv1[p * 256 + col];
                #pragma unroll
                for (int mi = 0; mi < 2; ++mi)
                    #pragma unroll
                    for (int r = 0; r < 4; ++r) {
                        int row = m0 + mi * 16 + q4 * 4 + r;
                        qkvout[(size_t)row * 768 + p * 256 + col] =
                            f2bfu(acc[mi][ni][r] + bb);
                    }
            }
        }
    }
}

// ---------------- attention: one wave per group (unchanged) ----------------
__global__ __launch_bounds__(256) void attn_wave(
    const ushort_t* __restrict__ q_all, int qld, int qoff, int qstride,
    const ushort_t* __restrict__ kv_all, int kvld, int koff, int voff,
    const int* __restrict__ kvidx, int ngroups, ushort_t* __restrict__ o_out) {
    __shared__ ushort_t KL[4][KVN][264];
    __shared__ ushort_t VL[4][KVN][264];
    const int w = threadIdx.x >> 6, lane = threadIdx.x & 63;
    const int g = blockIdx.x * 4 + w;
    if (g >= ngroups) return;

    int idx16 = 0;
    if (lane < KVN)
        idx16 = kvidx ? kvidx[g * KVN + lane] : g * SEQ + 1 + lane;

    float qv[4];
    {
        uint2 u = *reinterpret_cast<const uint2*>(
            q_all + (size_t)g * qstride * qld + qoff + lane * 4);
        qv[0] = bfu2f((ushort_t)(u.x & 0xffff));
        qv[1] = bfu2f((ushort_t)(u.x >> 16));
        qv[2] = bfu2f((ushort_t)(u.y & 0xffff));
        qv[3] = bfu2f((ushort_t)(u.y >> 16));
    }
    {
        const int r = lane & 15, qtr = lane >> 4;
        int rid = __shfl(idx16, r);
        const ushort_t* kb = kv_all + (size_t)rid * kvld + koff;
        const ushort_t* vb = kv_all + (size_t)rid * kvld + voff;
        #pragma unroll
        for (int j = 0; j < 8; ++j) {
            int c8 = (qtr * 8 + j) * 8;
            *reinterpret_cast<int4*>(&KL[w][r][c8]) = *reinterpret_cast<const int4*>(kb + c8);
            *reinterpret_cast<int4*>(&VL[w][r][c8]) = *reinterpret_cast<const int4*>(vb + c8);
        }
    }
    float att[KVN];
    #pragma unroll
    for (int k = 0; k < KVN; ++k) {
        uint2 u = *reinterpret_cast<const uint2*>(&KL[w][k][lane * 4]);
        float p = qv[0] * bfu2f((ushort_t)(u.x & 0xffff))
                + qv[1] * bfu2f((ushort_t)(u.x >> 16))
                + qv[2] * bfu2f((ushort_t)(u.y & 0xffff))
                + qv[3] * bfu2f((ushort_t)(u.y >> 16));
        p += __shfl_xor(p, 1);
        p += __shfl_xor(p, 2);
        p += __shfl_xor(p, 4);
        att[k] = p * 0.17677669529663687f;
    }
    float m = att[0];
    #pragma unroll
    for (int k = 1; k < KVN; ++k) m = fmaxf(m, att[k]);
    float sum = 0.f;
    #pragma unroll
    for (int k = 0; k < KVN; ++k) { att[k] = __expf(att[k] - m); sum += att[k]; }
    float inv = 1.f / sum;
    float o[4] = {0.f, 0.f, 0.f, 0.f};
    #pragma unroll
    for (int k = 0; k < KVN; ++k) {
        uint2 u = *reinterpret_cast<const uint2*>(&VL[w][k][lane * 4]);
        float a = att[k] * inv;
        o[0] += a * bfu2f((ushort_t)(u.x & 0xffff));
        o[1] += a * bfu2f((ushort_t)(u.x >> 16));
        o[2] += a * bfu2f((ushort_t)(u.y & 0xffff));
        o[3] += a * bfu2f((ushort_t)(u.y >> 16));
    }
    uint2 r;
    r.x = (unsigned)f2bfu(o[0]) | ((unsigned)f2bfu(o[1]) << 16);
    r.y = (unsigned)f2bfu(o[2]) | ((unsigned)f2bfu(o[3]) << 16);
    *reinterpret_cast<uint2*>(o_out + (size_t)g * 256 + lane * 4) = r;
}

// ---------------- output head (unchanged) ----------------
__global__ __launch_bounds__(64) void k_out(
    const ushort_t* __restrict__ h2, const float* __restrict__ W_out,
    const float* __restrict__ b_out, float* __restrict__ out) {
    const int b = blockIdx.x, j = threadIdx.x;
    __shared__ float xr[HDIM];
    for (int k = j; k < HDIM; k += 64) xr[k] = bfu2f(h2[(size_t)b * HDIM + k]);
    __syncthreads();
    float logit = -1e30f;
    if (j < OUTD) {
        float acc = b_out[j];
        for (int k = 0; k < HDIM; ++k) acc += xr[k] * W_out[k * OUTD + j];
        logit = acc;
    }
    float m = logit;
    #pragma unroll
    for (int off = 32; off > 0; off >>= 1) m = fmaxf(m, __shfl_xor(m, off));
    float e = (j < OUTD) ? __expf(logit - m) : 0.f;
    float s = e;
    #pragma unroll
    for (int off = 32; off > 0; off >>= 1) s += __shfl_xor(s, off);
    if (j < OUTD) out[(size_t)b * OUTD + j] = e / s;
}

extern "C" void kernel_launch(void* const* d_in, const int* in_sizes, int n_in,
                              void* d_out, int out_size, void* d_ws, size_t ws_size,
                              hipStream_t stream) {
    const float* nf    = (const float*)d_in[0];
    const int*   batch = (const int*)d_in[1];
    const int*   nbr2  = (const int*)d_in[2];
    const int*   nbr1  = (const int*)d_in[3];
    const float* W_in  = (const float*)d_in[4];
    const float* b_in  = (const float*)d_in[5];
    const float* Wqkv  = (const float*)d_in[6];
    const float* bqkv  = (const float*)d_in[7];
    const float* Wo    = (const float*)d_in[8];
    const float* bo    = (const float*)d_in[9];
    const float* Wf    = (const float*)d_in[10];
    const float* bf    = (const float*)d_in[11];
    const float* ln_g  = (const float*)d_in[12];
    const float* ln_b  = (const float*)d_in[13];
    const float* W_out = (const float*)d_in[14];
    const float* b_out = (const float*)d_in[15];
    float* out = (float*)d_out;
    char* ws = (char*)d_ws;

    ushort_t* h0   = (ushort_t*)(ws + OFF_H0);
    ushort_t* kv0  = (ushort_t*)(ws + OFF_KV0);
    ushort_t* q0   = (ushort_t*)(ws + OFF_Q0);
    ushort_t* o0   = (ushort_t*)(ws + OFF_O0);
    ushort_t* h1   = (ushort_t*)(ws + OFF_H1);
    ushort_t* qkv1 = (ushort_t*)(ws + OFF_QKV1);
    ushort_t* o1   = (ushort_t*)(ws + OFF_O1);
    ushort_t* h2   = (ushort_t*)(ws + OFF_H2);
    const int* ids1 = (const int*)(ws + OFF_IDS);

    hipLaunchKernelGGL(k_prep, dim3(256, 13), dim3(256), 0, stream,
                       W_in, Wqkv, Wo, Wf, bqkv, batch, nbr2, ws);
    // h0 = relu(nf @ W_in + b): persistent, grid 1024
    hipLaunchKernelGGL(k_h0, dim3(H0GRID), dim3(256), 0, stream,
                       nf, (const ushort_t*)(ws + OFF_WTIN), b_in, h0);
    // kv0 + q0 (weight-stationary)
    hipLaunchKernelGGL(k_kvq, dim3(256), dim3(512), 0, stream,
                       h0, (const ushort_t*)(ws + OFF_WKV0),
                       (const ushort_t*)(ws + OFF_WQ0), bqkv, ids1, kv0, q0);
    // A0
    hipLaunchKernelGGL(attn_wave, dim3(N1 / 4), dim3(256), 0, stream,
                       q0, 256, 0, 1, kv0, 512, 0, 256, nbr1, N1, o0);
    // FFN0 (+ fused qkv1), residual = h0[ids1]
    hipLaunchKernelGGL(k_ffn, dim3(N1 / 32), dim3(256), 0, stream,
                       o0, (const ushort_t*)(ws + OFF_WO0), bo,
                       h0, ids1, 1, ln_g, ln_b,
                       (const ushort_t*)(ws + OFF_WF0), bf,
                       ln_g + 256, ln_b + 256, h1,
                       (const ushort_t*)(ws + OFF_WKVQ1),
                       (const float*)(ws + OFF_B1), qkv1);
    // A1
    hipLaunchKernelGGL(attn_wave, dim3(B_SZ / 4), dim3(256), 0, stream,
                       qkv1, 768, 512, 17, qkv1, 768, 0, 256,
                       (const int*)nullptr, B_SZ, o1);
    // FFN1 (no qkv), residual = h1[17b]
    hipLaunchKernelGGL(k_ffn, dim3(B_SZ / 32), dim3(256), 0, stream,
                       o1, (const ushort_t*)(ws + OFF_WO1), bo + 256,
                       h1, (const int*)nullptr, 17, ln_g + 512, ln_b + 512,
                       (const ushort_t*)(ws + OFF_WF1), bf + 256,
                       ln_g + 768, ln_b + 768, h2,
                       (const ushort_t*)nullptr, (const float*)nullptr,
                       (ushort_t*)nullptr);
    hipLaunchKernelGGL(k_out, dim3(B_SZ), dim3(64), 0, stream,
                       h2, W_out, b_out, out);
}

// Round 17
// 281.939 us; speedup vs baseline: 1.0725x; 1.0075x over previous
//
#include <hip/hip_runtime.h>
#include <hip/hip_bf16.h>
#include <math.h>

typedef unsigned short ushort_t;
typedef __bf16 bf16x8 __attribute__((ext_vector_type(8)));
typedef float  f32x4  __attribute__((ext_vector_type(4)));
typedef __attribute__((address_space(1))) const unsigned int* gas_t;
typedef __attribute__((address_space(3))) unsigned int* las_t;

#define B_SZ   1024
#define SEQ    17
#define KVN    16
#define HDIM   256
#define NHEAD  8
#define DH     32
#define INF    150
#define OUTD   22
#define LN_EPS 1e-5f
#define N1     (B_SZ * SEQ)      // 17408
#define NN_    100000
#define NKVBLK 1563              // ceil(100000/64)  (k_kvq tiles)
#define NQBLK  272               // 17408/64
#define NH0BLK 3125              // 100000/32 exact  (k_h0 tiles)

// ---------------- workspace layout (bytes) ----------------
constexpr size_t SZ_H0    = (size_t)NN_ * 256 * 2;
constexpr size_t SZ_KV0   = (size_t)NN_ * 512 * 2;
constexpr size_t SZ_ROW   = (size_t)N1 * 256 * 2;
constexpr size_t OFF_H0   = 0;
constexpr size_t OFF_KV0  = OFF_H0 + SZ_H0;
constexpr size_t OFF_QKV1 = OFF_KV0;                       // alias (KV0 dead after A0)
constexpr size_t OFF_O1   = OFF_QKV1 + (size_t)N1 * 768 * 2;
constexpr size_t OFF_H2   = OFF_O1 + (size_t)B_SZ * 256 * 2;
constexpr size_t OFF_Q0   = OFF_KV0 + SZ_KV0;
constexpr size_t OFF_O0   = OFF_Q0 + SZ_ROW;
constexpr size_t OFF_H1   = OFF_O0;                        // alias (o0 dead after FFN0 stage)
constexpr size_t OFF_IDS  = OFF_O0 + SZ_ROW;
constexpr size_t OFF_WTIN = OFF_IDS + (size_t)N1 * 4;
constexpr size_t OFF_WKV0 = OFF_WTIN + 256 * 160 * 2;
constexpr size_t OFF_WQ0  = OFF_WKV0 + 512 * 256 * 2;
constexpr size_t OFF_WKVQ1= OFF_WQ0 + 256 * 256 * 2;
constexpr size_t OFF_WO0  = OFF_WKVQ1 + 768 * 256 * 2;
constexpr size_t OFF_WF0  = OFF_WO0 + 256 * 256 * 2;
constexpr size_t OFF_WO1  = OFF_WF0 + 256 * 256 * 2;
constexpr size_t OFF_WF1  = OFF_WO1 + 256 * 256 * 2;
constexpr size_t OFF_B1   = OFF_WF1 + 256 * 256 * 2;

__device__ __forceinline__ ushort_t f2bfu(float x) {
    __hip_bfloat16 h = __float2bfloat16(x);
    return *reinterpret_cast<ushort_t*>(&h);
}
__device__ __forceinline__ float bfu2f(ushort_t u) {
    __hip_bfloat16 h;
    *reinterpret_cast<ushort_t*>(&h) = u;
    return __bfloat162float(h);
}
__device__ __forceinline__ f32x4 mfma16(bf16x8 a, bf16x8 b, f32x4 c) {
    return __builtin_amdgcn_mfma_f32_16x16x32_bf16(a, b, c, 0, 0, 0);
}

// ---------------- prep (unchanged) ----------------
__global__ __launch_bounds__(256) void k_prep(
    const float* __restrict__ W_in, const float* __restrict__ Wqkv,
    const float* __restrict__ Wo, const float* __restrict__ Wf,
    const float* __restrict__ bqkv,
    const int* __restrict__ batch, const int* __restrict__ nbr2,
    char* __restrict__ ws) {
    const int job = blockIdx.y;
    const int idx = blockIdx.x * 256 + threadIdx.x;
    if (job == 11) {
        if (idx < N1) {
            int b = idx / SEQ, s = idx % SEQ;
            ((int*)(ws + OFF_IDS))[idx] = (s == 0) ? batch[b] : nbr2[b * KVN + s - 1];
        }
        return;
    }
    if (job == 12) {
        if (idx < 768) ((float*)(ws + OFF_B1))[idx] = bqkv[768 + ((idx + 256) % 768)];
        return;
    }
    const float* src = nullptr; ushort_t* dst = nullptr;
    int Kpad = 256, Kvalid = 256;
    switch (job) {
        case 0:  src = W_in;           dst = (ushort_t*)(ws + OFF_WTIN); Kpad = 160; Kvalid = 150; break;
        case 1:  src = Wqkv + 65536;   dst = (ushort_t*)(ws + OFF_WKV0); break;
        case 2:  src = Wqkv + 131072;  dst = (ushort_t*)(ws + OFF_WKV0) + 65536; break;
        case 3:  src = Wqkv;           dst = (ushort_t*)(ws + OFF_WQ0); break;
        case 4:  src = Wqkv + 262144;  dst = (ushort_t*)(ws + OFF_WKVQ1); break;
        case 5:  src = Wqkv + 327680;  dst = (ushort_t*)(ws + OFF_WKVQ1) + 65536; break;
        case 6:  src = Wqkv + 196608;  dst = (ushort_t*)(ws + OFF_WKVQ1) + 131072; break;
        case 7:  src = Wo;             dst = (ushort_t*)(ws + OFF_WO0); break;
        case 8:  src = Wo + 65536;     dst = (ushort_t*)(ws + OFF_WO1); break;
        case 9:  src = Wf;             dst = (ushort_t*)(ws + OFF_WF0); break;
        case 10: src = Wf + 65536;     dst = (ushort_t*)(ws + OFF_WF1); break;
    }
    const int total = 256 * Kpad;
    if (idx >= total) return;
    int n = idx / Kpad, k = idx % Kpad;
    dst[idx] = (k < Kvalid) ? f2bfu(src[(size_t)k * 256 + n]) : (ushort_t)0;
}

// ====== k_h0: h0 = relu(nf @ W_in + b) — 32-row tile per block ======
// grid 3125 (exact), 256 thr, (256,2). Small footprint (~90 VGPR) -> no
// spill AND 4+ blocks/CU. LDS 12.3 KB.
__global__ __launch_bounds__(256, 2) void k_h0(
    const float* __restrict__ nf, const ushort_t* __restrict__ Wt_in,
    const float* __restrict__ b_in, ushort_t* __restrict__ h0) {
    __shared__ ushort_t As[32 * 192];    // 12.3 KB, XOR-swizzled
    const int tid = threadIdx.x;
    const int lane = tid & 63, w = tid >> 6;
    const int lr = lane & 15, q4 = lane >> 4;
    const int m0 = blockIdx.x * 32;

    // stage A: 32 rows x 160 cols f32->bf16 (640 chunks = 2.5/thread)
    #pragma unroll
    for (int i = 0; i < 3; ++i) {
        int flat = tid + i * 256;
        if (flat < 640) {
            int row = flat / 20, c = flat % 20;
            const float* ap = nf + (size_t)(m0 + row) * INF + c * 8;
            ushort_t tmp[8];
            if (c < 18) {
                #pragma unroll
                for (int j = 0; j < 4; ++j) {
                    float2 f = *reinterpret_cast<const float2*>(ap + j * 2);
                    tmp[j * 2] = f2bfu(f.x); tmp[j * 2 + 1] = f2bfu(f.y);
                }
            } else {
                #pragma unroll
                for (int j = 0; j < 8; ++j) {
                    int k = c * 8 + j;
                    tmp[j] = (k < INF) ? f2bfu(ap[j]) : (ushort_t)0;
                }
            }
            *reinterpret_cast<int4*>(&As[row * 192 + (c ^ (row & 7)) * 8]) =
                *reinterpret_cast<int4*>(tmp);
        }
    }
    __syncthreads();

    f32x4 acc[2][4] = {};
    #pragma unroll
    for (int s = 0; s < 5; ++s) {
        bf16x8 a[2], b[4];
        #pragma unroll
        for (int mi = 0; mi < 2; ++mi) {
            int row = mi * 16 + lr;
            a[mi] = *reinterpret_cast<const bf16x8*>(
                &As[row * 192 + (((s * 4 + q4) ^ (row & 7)) * 8)]);
        }
        #pragma unroll
        for (int ni = 0; ni < 4; ++ni)
            b[ni] = *reinterpret_cast<const bf16x8*>(
                Wt_in + (size_t)(w * 64 + ni * 16 + lr) * 160 + s * 32 + q4 * 8);
        #pragma unroll
        for (int mi = 0; mi < 2; ++mi)
            #pragma unroll
            for (int ni = 0; ni < 4; ++ni)
                acc[mi][ni] = mfma16(a[mi], b[ni], acc[mi][ni]);
    }
    #pragma unroll
    for (int ni = 0; ni < 4; ++ni) {
        float bb = b_in[w * 64 + ni * 16 + lr];
        #pragma unroll
        for (int mi = 0; mi < 2; ++mi)
            #pragma unroll
            for (int r = 0; r < 4; ++r) {
                int grow = m0 + mi * 16 + q4 * 4 + r;
                h0[(size_t)grow * 256 + w * 64 + ni * 16 + lr] =
                    f2bfu(fmaxf(acc[mi][ni][r] + bb, 0.f));
            }
    }
}

// ====== k_kvq (unchanged from r13) ==========================================
__global__ __launch_bounds__(512, 2) void k_kvq(
    const ushort_t* __restrict__ h0, const ushort_t* __restrict__ Wkv,
    const ushort_t* __restrict__ Wq, const float* __restrict__ bqkv,
    const int* __restrict__ ids1, ushort_t* __restrict__ kv0,
    ushort_t* __restrict__ q0) {
    __shared__ ushort_t As[64 * 256];    // 32 KB
    const int tid = threadIdx.x;
    const int lane = tid & 63, w = tid >> 6;
    const int lr = lane & 15, q4 = lane >> 4;
    const bool isv = w >= 4;
    const int n0 = (w & 3) * 64;

    const ushort_t* Wsrc = Wkv + (isv ? 65536 : 0);
    bf16x8 bw[4][8];
    #pragma unroll
    for (int ni = 0; ni < 4; ++ni)
        #pragma unroll
        for (int s = 0; s < 8; ++s)
            bw[ni][s] = *reinterpret_cast<const bf16x8*>(
                Wsrc + (size_t)(n0 + ni * 16 + lr) * 256 + s * 32 + q4 * 8);
    float bb[4];
    #pragma unroll
    for (int ni = 0; ni < 4; ++ni)
        bb[ni] = bqkv[256 + (isv ? 256 : 0) + n0 + ni * 16 + lr];
    const int cbase = (isv ? 256 : 0) + n0;

    for (int t = blockIdx.x; t < NKVBLK; t += 256) {
        const int m0 = t * 64;
        __syncthreads();
        #pragma unroll
        for (int i = 0; i < 4; ++i) {
            int flat = tid + i * 512;
            int row = flat >> 5, ch = flat & 31;
            int gm = m0 + row; if (gm >= NN_) gm = 0;
            const ushort_t* src = h0 + (size_t)gm * 256 + ((ch ^ (row & 7)) * 8);
            __builtin_amdgcn_global_load_lds(
                (gas_t)(const void*)src,
                (las_t)(void*)(As + (size_t)(i * 512 + w * 64) * 8), 16, 0, 0);
        }
        __syncthreads();
        f32x4 acc[4][4] = {};
        #pragma unroll
        for (int s = 0; s < 8; ++s) {
            bf16x8 a[4];
            #pragma unroll
            for (int mi = 0; mi < 4; ++mi)
                a[mi] = *reinterpret_cast<const bf16x8*>(
                    &As[(mi * 16 + lr) * 256 + (((s * 4 + q4) ^ (lr & 7)) * 8)]);
            #pragma unroll
            for (int mi = 0; mi < 4; ++mi)
                #pragma unroll
                for (int ni = 0; ni < 4; ++ni)
                    acc[mi][ni] = mfma16(a[mi], bw[ni][s], acc[mi][ni]);
        }
        #pragma unroll
        for (int ni = 0; ni < 4; ++ni)
            #pragma unroll
            for (int mi = 0; mi < 4; ++mi)
                #pragma unroll
                for (int r = 0; r < 4; ++r) {
                    int grow = m0 + mi * 16 + q4 * 4 + r;
                    if (grow < NN_)
                        kv0[(size_t)grow * 512 + cbase + ni * 16 + lr] =
                            f2bfu(acc[mi][ni][r] + bb[ni]);
                }
    }

    const int n0q = w * 32;
    bf16x8 bq[2][8];
    #pragma unroll
    for (int ni = 0; ni < 2; ++ni)
        #pragma unroll
        for (int s = 0; s < 8; ++s)
            bq[ni][s] = *reinterpret_cast<const bf16x8*>(
                Wq + (size_t)(n0q + ni * 16 + lr) * 256 + s * 32 + q4 * 8);
    float bbq[2];
    #pragma unroll
    for (int ni = 0; ni < 2; ++ni) bbq[ni] = bqkv[n0q + ni * 16 + lr];

    for (int t = blockIdx.x; t < NQBLK; t += 256) {
        const int m0 = t * 64;
        __syncthreads();
        #pragma unroll
        for (int i = 0; i < 4; ++i) {
            int flat = tid + i * 512;
            int row = flat >> 5, ch = flat & 31;
            int rid = ids1[m0 + row];
            const ushort_t* src = h0 + (size_t)rid * 256 + ((ch ^ (row & 7)) * 8);
            __builtin_amdgcn_global_load_lds(
                (gas_t)(const void*)src,
                (las_t)(void*)(As + (size_t)(i * 512 + w * 64) * 8), 16, 0, 0);
        }
        __syncthreads();
        f32x4 acc[4][2] = {};
        #pragma unroll
        for (int s = 0; s < 8; ++s) {
            bf16x8 a[4];
            #pragma unroll
            for (int mi = 0; mi < 4; ++mi)
                a[mi] = *reinterpret_cast<const bf16x8*>(
                    &As[(mi * 16 + lr) * 256 + (((s * 4 + q4) ^ (lr & 7)) * 8)]);
            #pragma unroll
            for (int mi = 0; mi < 4; ++mi)
                #pragma unroll
                for (int ni = 0; ni < 2; ++ni)
                    acc[mi][ni] = mfma16(a[mi], bq[ni][s], acc[mi][ni]);
        }
        #pragma unroll
        for (int ni = 0; ni < 2; ++ni)
            #pragma unroll
            for (int mi = 0; mi < 4; ++mi)
                #pragma unroll
                for (int r = 0; r < 4; ++r) {
                    int grow = m0 + mi * 16 + q4 * 4 + r;
                    q0[(size_t)grow * 256 + n0q + ni * 16 + lr] =
                        f2bfu(acc[mi][ni][r] + bbq[ni]);
                }
    }
}

// ======= k_ffn (unchanged from r13) =======
__global__ __launch_bounds__(256) void k_ffn(
    const ushort_t* __restrict__ Ain, const ushort_t* __restrict__ W1t,
    const float* __restrict__ b1,
    const ushort_t* __restrict__ resmat, const int* __restrict__ residx, int rstride,
    const float* __restrict__ lng1, const float* __restrict__ lnb1,
    const ushort_t* __restrict__ W2t, const float* __restrict__ b2,
    const float* __restrict__ lng2, const float* __restrict__ lnb2,
    ushort_t* __restrict__ out,
    const ushort_t* __restrict__ Wqkv1t, const float* __restrict__ bqkv1,
    ushort_t* __restrict__ qkvout) {
    __shared__ ushort_t Al[32][264];
    __shared__ float xr[32][260];
    __shared__ float mrow[32], rrow[32];
    __shared__ int sidx[32];
    const int tid = threadIdx.x;
    const int m0 = blockIdx.x * 32;
    const int lane = tid & 63, w = tid >> 6;
    const int lr = lane & 15, q4 = lane >> 4, lk = q4 * 8;

    #pragma unroll
    for (int j = 0; j < 4; ++j) {
        int flat = tid + j * 256;
        int row = flat >> 5, ch = flat & 31;
        *reinterpret_cast<int4*>(&Al[row][ch * 8]) =
            *reinterpret_cast<const int4*>(Ain + (size_t)(m0 + row) * 256 + ch * 8);
    }
    if (tid < 32) sidx[tid] = residx ? residx[m0 + tid] : (m0 + tid) * rstride;
    __syncthreads();

    f32x4 acc[2][4];
    #pragma unroll
    for (int g = 0; g < 2; ++g) {
        const ushort_t* Wt = g ? W2t : W1t;
        #pragma unroll
        for (int mi = 0; mi < 2; ++mi)
            #pragma unroll
            for (int ni = 0; ni < 4; ++ni) acc[mi][ni] = f32x4{0.f, 0.f, 0.f, 0.f};
        bf16x8 bc[4];
        #pragma unroll
        for (int ni = 0; ni < 4; ++ni)
            bc[ni] = *reinterpret_cast<const bf16x8*>(
                Wt + (size_t)(w * 64 + ni * 16 + lr) * 256 + lk);
        #pragma unroll
        for (int s = 0; s < 8; ++s) {
            bf16x8 bn[4];
            if (s < 7) {
                #pragma unroll
                for (int ni = 0; ni < 4; ++ni)
                    bn[ni] = *reinterpret_cast<const bf16x8*>(
                        Wt + (size_t)(w * 64 + ni * 16 + lr) * 256 + (s + 1) * 32 + lk);
            }
            bf16x8 a0 = *reinterpret_cast<const bf16x8*>(&Al[lr][s * 32 + lk]);
            bf16x8 a1 = *reinterpret_cast<const bf16x8*>(&Al[16 + lr][s * 32 + lk]);
            #pragma unroll
            for (int ni = 0; ni < 4; ++ni) {
                acc[0][ni] = mfma16(a0, bc[ni], acc[0][ni]);
                acc[1][ni] = mfma16(a1, bc[ni], acc[1][ni]);
            }
            if (s < 7) {
                #pragma unroll
                for (int ni = 0; ni < 4; ++ni) bc[ni] = bn[ni];
            }
        }
        #pragma unroll
        for (int mi = 0; mi < 2; ++mi)
            #pragma unroll
            for (int ni = 0; ni < 4; ++ni)
                #pragma unroll
                for (int r = 0; r < 4; ++r)
                    xr[mi * 16 + q4 * 4 + r][w * 64 + ni * 16 + lr] = acc[mi][ni][r];
        __syncthreads();
        {
            float bb = g ? b2[tid] : b1[tid];
            if (g == 0) {
                for (int r = 0; r < 32; ++r)
                    xr[r][tid] += bb + bfu2f(resmat[(size_t)sidx[r] * 256 + tid]);
            } else {
                for (int r = 0; r < 32; ++r)
                    xr[r][tid] += bb + bfu2f(Al[r][tid]);   // ha residual from LDS
            }
        }
        __syncthreads();
        for (int rr = w * 8; rr < w * 8 + 8; ++rr) {
            float4 v = *reinterpret_cast<const float4*>(&xr[rr][lane * 4]);
            float s1 = v.x + v.y + v.z + v.w;
            float s2 = v.x * v.x + v.y * v.y + v.z * v.z + v.w * v.w;
            #pragma unroll
            for (int off = 32; off > 0; off >>= 1) {
                s1 += __shfl_xor(s1, off);
                s2 += __shfl_xor(s2, off);
            }
            if (lane == 0) {
                float m = s1 * (1.f / 256.f);
                float var = s2 * (1.f / 256.f) - m * m;
                mrow[rr] = m;
                rrow[rr] = rsqrtf(var + LN_EPS);
            }
        }
        __syncthreads();
        if (g == 0) {
            float gg = lng1[tid], bb = lnb1[tid];
            for (int r = 0; r < 32; ++r)
                Al[r][tid] = f2bfu((xr[r][tid] - mrow[r]) * rrow[r] * gg + bb);
        } else {
            float gg = lng2[tid], bb = lnb2[tid];
            for (int r = 0; r < 32; ++r) {
                float v = (xr[r][tid] - mrow[r]) * rrow[r] * gg + bb;
                ushort_t uv = f2bfu(v);
                out[(size_t)(m0 + r) * 256 + tid] = uv;
                if (qkvout) Al[r][tid] = uv;       // h1 tile stays in LDS
            }
        }
        __syncthreads();
    }

    if (qkvout) {
        for (int p = 0; p < 3; ++p) {
            #pragma unroll
            for (int mi = 0; mi < 2; ++mi)
                #pragma unroll
                for (int ni = 0; ni < 4; ++ni) acc[mi][ni] = f32x4{0.f, 0.f, 0.f, 0.f};
            const ushort_t* Wt = Wqkv1t + (size_t)p * 256 * 256;
            bf16x8 bc[4];
            #pragma unroll
            for (int ni = 0; ni < 4; ++ni)
                bc[ni] = *reinterpret_cast<const bf16x8*>(
                    Wt + (size_t)(w * 64 + ni * 16 + lr) * 256 + lk);
            #pragma unroll
            for (int s = 0; s < 8; ++s) {
                bf16x8 bn[4];
                if (s < 7) {
                    #pragma unroll
                    for (int ni = 0; ni < 4; ++ni)
                        bn[ni] = *reinterpret_cast<const bf16x8*>(
                            Wt + (size_t)(w * 64 + ni * 16 + lr) * 256 + (s + 1) * 32 + lk);
                }
                bf16x8 a0 = *reinterpret_cast<const bf16x8*>(&Al[lr][s * 32 + lk]);
                bf16x8 a1 = *reinterpret_cast<const bf16x8*>(&Al[16 + lr][s * 32 + lk]);
                #pragma unroll
                for (int ni = 0; ni < 4; ++ni) {
                    acc[0][ni] = mfma16(a0, bc[ni], acc[0][ni]);
                    acc[1][ni] = mfma16(a1, bc[ni], acc[1][ni]);
                }
                if (s < 7) {
                    #pragma unroll
                    for (int ni = 0; ni < 4; ++ni) bc[ni] = bn[ni];
                }
            }
            #pragma unroll
            for (int ni = 0; ni < 4; ++ni) {
                int col = w * 64 + ni * 16 + lr;
                float bb = bqkv1[p * 256 + col];
                #pragma unroll
                for (int mi = 0; mi < 2; ++mi)
                    #pragma unroll
                    for (int r = 0; r < 4; ++r) {
                        int row = m0 + mi * 16 + q4 * 4 + r;
                        qkvout[(size_t)row * 768 + p * 256 + col] =
                            f2bfu(acc[mi][ni][r] + bb);
                    }
            }
        }
    }
}

// ---------------- attention: one wave per group (unchanged) ----------------
__global__ __launch_bounds__(256) void attn_wave(
    const ushort_t* __restrict__ q_all, int qld, int qoff, int qstride,
    const ushort_t* __restrict__ kv_all, int kvld, int koff, int voff,
    const int* __restrict__ kvidx, int ngroups, ushort_t* __restrict__ o_out) {
    __shared__ ushort_t KL[4][KVN][264];
    __shared__ ushort_t VL[4][KVN][264];
    const int w = threadIdx.x >> 6, lane = threadIdx.x & 63;
    const int g = blockIdx.x * 4 + w;
    if (g >= ngroups) return;

    int idx16 = 0;
    if (lane < KVN)
        idx16 = kvidx ? kvidx[g * KVN + lane] : g * SEQ + 1 + lane;

    float qv[4];
    {
        uint2 u = *reinterpret_cast<const uint2*>(
            q_all + (size_t)g * qstride * qld + qoff + lane * 4);
        qv[0] = bfu2f((ushort_t)(u.x & 0xffff));
        qv[1] = bfu2f((ushort_t)(u.x >> 16));
        qv[2] = bfu2f((ushort_t)(u.y & 0xffff));
        qv[3] = bfu2f((ushort_t)(u.y >> 16));
    }
    {
        const int r = lane & 15, qtr = lane >> 4;
        int rid = __shfl(idx16, r);
        const ushort_t* kb = kv_all + (size_t)rid * kvld + koff;
        const ushort_t* vb = kv_all + (size_t)rid * kvld + voff;
        #pragma unroll
        for (int j = 0; j < 8; ++j) {
            int c8 = (qtr * 8 + j) * 8;
            *reinterpret_cast<int4*>(&KL[w][r][c8]) = *reinterpret_cast<const int4*>(kb + c8);
            *reinterpret_cast<int4*>(&VL[w][r][c8]) = *reinterpret_cast<const int4*>(vb + c8);
        }
    }
    float att[KVN];
    #pragma unroll
    for (int k = 0; k < KVN; ++k) {
        uint2 u = *reinterpret_cast<const uint2*>(&KL[w][k][lane * 4]);
        float p = qv[0] * bfu2f((ushort_t)(u.x & 0xffff))
                + qv[1] * bfu2f((ushort_t)(u.x >> 16))
                + qv[2] * bfu2f((ushort_t)(u.y & 0xffff))
                + qv[3] * bfu2f((ushort_t)(u.y >> 16));
        p += __shfl_xor(p, 1);
        p += __shfl_xor(p, 2);
        p += __shfl_xor(p, 4);
        att[k] = p * 0.17677669529663687f;
    }
    float m = att[0];
    #pragma unroll
    for (int k = 1; k < KVN; ++k) m = fmaxf(m, att[k]);
    float sum = 0.f;
    #pragma unroll
    for (int k = 0; k < KVN; ++k) { att[k] = __expf(att[k] - m); sum += att[k]; }
    float inv = 1.f / sum;
    float o[4] = {0.f, 0.f, 0.f, 0.f};
    #pragma unroll
    for (int k = 0; k < KVN; ++k) {
        uint2 u = *reinterpret_cast<const uint2*>(&VL[w][k][lane * 4]);
        float a = att[k] * inv;
        o[0] += a * bfu2f((ushort_t)(u.x & 0xffff));
        o[1] += a * bfu2f((ushort_t)(u.x >> 16));
        o[2] += a * bfu2f((ushort_t)(u.y & 0xffff));
        o[3] += a * bfu2f((ushort_t)(u.y >> 16));
    }
    uint2 r;
    r.x = (unsigned)f2bfu(o[0]) | ((unsigned)f2bfu(o[1]) << 16);
    r.y = (unsigned)f2bfu(o[2]) | ((unsigned)f2bfu(o[3]) << 16);
    *reinterpret_cast<uint2*>(o_out + (size_t)g * 256 + lane * 4) = r;
}

// ---------------- output head (unchanged) ----------------
__global__ __launch_bounds__(64) void k_out(
    const ushort_t* __restrict__ h2, const float* __restrict__ W_out,
    const float* __restrict__ b_out, float* __restrict__ out) {
    const int b = blockIdx.x, j = threadIdx.x;
    __shared__ float xr[HDIM];
    for (int k = j; k < HDIM; k += 64) xr[k] = bfu2f(h2[(size_t)b * HDIM + k]);
    __syncthreads();
    float logit = -1e30f;
    if (j < OUTD) {
        float acc = b_out[j];
        for (int k = 0; k < HDIM; ++k) acc += xr[k] * W_out[k * OUTD + j];
        logit = acc;
    }
    float m = logit;
    #pragma unroll
    for (int off = 32; off > 0; off >>= 1) m = fmaxf(m, __shfl_xor(m, off));
    float e = (j < OUTD) ? __expf(logit - m) : 0.f;
    float s = e;
    #pragma unroll
    for (int off = 32; off > 0; off >>= 1) s += __shfl_xor(s, off);
    if (j < OUTD) out[(size_t)b * OUTD + j] = e / s;
}

extern "C" void kernel_launch(void* const* d_in, const int* in_sizes, int n_in,
                              void* d_out, int out_size, void* d_ws, size_t ws_size,
                              hipStream_t stream) {
    const float* nf    = (const float*)d_in[0];
    const int*   batch = (const int*)d_in[1];
    const int*   nbr2  = (const int*)d_in[2];
    const int*   nbr1  = (const int*)d_in[3];
    const float* W_in  = (const float*)d_in[4];
    const float* b_in  = (const float*)d_in[5];
    const float* Wqkv  = (const float*)d_in[6];
    const float* bqkv  = (const float*)d_in[7];
    const float* Wo    = (const float*)d_in[8];
    const float* bo    = (const float*)d_in[9];
    const float* Wf    = (const float*)d_in[10];
    const float* bf    = (const float*)d_in[11];
    const float* ln_g  = (const float*)d_in[12];
    const float* ln_b  = (const float*)d_in[13];
    const float* W_out = (const float*)d_in[14];
    const float* b_out = (const float*)d_in[15];
    float* out = (float*)d_out;
    char* ws = (char*)d_ws;

    ushort_t* h0   = (ushort_t*)(ws + OFF_H0);
    ushort_t* kv0  = (ushort_t*)(ws + OFF_KV0);
    ushort_t* q0   = (ushort_t*)(ws + OFF_Q0);
    ushort_t* o0   = (ushort_t*)(ws + OFF_O0);
    ushort_t* h1   = (ushort_t*)(ws + OFF_H1);
    ushort_t* qkv1 = (ushort_t*)(ws + OFF_QKV1);
    ushort_t* o1   = (ushort_t*)(ws + OFF_O1);
    ushort_t* h2   = (ushort_t*)(ws + OFF_H2);
    const int* ids1 = (const int*)(ws + OFF_IDS);

    hipLaunchKernelGGL(k_prep, dim3(256, 13), dim3(256), 0, stream,
                       W_in, Wqkv, Wo, Wf, bqkv, batch, nbr2, ws);
    // h0 = relu(nf @ W_in + b): 32-row tiles, grid 3125
    hipLaunchKernelGGL(k_h0, dim3(NH0BLK), dim3(256), 0, stream,
                       nf, (const ushort_t*)(ws + OFF_WTIN), b_in, h0);
    // kv0 + q0 (weight-stationary)
    hipLaunchKernelGGL(k_kvq, dim3(256), dim3(512), 0, stream,
                       h0, (const ushort_t*)(ws + OFF_WKV0),
                       (const ushort_t*)(ws + OFF_WQ0), bqkv, ids1, kv0, q0);
    // A0
    hipLaunchKernelGGL(attn_wave, dim3(N1 / 4), dim3(256), 0, stream,
                       q0, 256, 0, 1, kv0, 512, 0, 256, nbr1, N1, o0);
    // FFN0 (+ fused qkv1), residual = h0[ids1]
    hipLaunchKernelGGL(k_ffn, dim3(N1 / 32), dim3(256), 0, stream,
                       o0, (const ushort_t*)(ws + OFF_WO0), bo,
                       h0, ids1, 1, ln_g, ln_b,
                       (const ushort_t*)(ws + OFF_WF0), bf,
                       ln_g + 256, ln_b + 256, h1,
                       (const ushort_t*)(ws + OFF_WKVQ1),
                       (const float*)(ws + OFF_B1), qkv1);
    // A1
    hipLaunchKernelGGL(attn_wave, dim3(B_SZ / 4), dim3(256), 0, stream,
                       qkv1, 768, 512, 17, qkv1, 768, 0, 256,
                       (const int*)nullptr, B_SZ, o1);
    // FFN1 (no qkv), residual = h1[17b]
    hipLaunchKernelGGL(k_ffn, dim3(B_SZ / 32), dim3(256), 0, stream,
                       o1, (const ushort_t*)(ws + OFF_WO1), bo + 256,
                       h1, (const int*)nullptr, 17, ln_g + 512, ln_b + 512,
                       (const ushort_t*)(ws + OFF_WF1), bf + 256,
                       ln_g + 768, ln_b + 768, h2,
                       (const ushort_t*)nullptr, (const float*)nullptr,
                       (ushort_t*)nullptr);
    hipLaunchKernelGGL(k_out, dim3(B_SZ), dim3(64), 0, stream,
                       h2, W_out, b_out, out);
}